// Round 3
// baseline (119.524 us; speedup 1.0000x reference)
//
#include <hip/hip_runtime.h>
#include <math.h>

// HypAgg (Poincare ball, c=1), fully fused single dispatch.
//   g_ij = att_ij * atanh(sn_ij)/sn_ij / den_ij
//   support_i = beta_i * ( -S_i x_i + beta_i Y_i ),  S=sum g*alpha, Y=sum g x_j
// Grid (64 i-tiles x 8 j-chunks). Per-row stats computed inline during staging.
// Cross-block: each block writes Yp/Sp partials + release-stores a MAGIC flag;
// owner block (chunk == tile&7) acquire-spins on 8 flags, then sums + expmap.
// ws floats: Yp[8*131072] | Sp[8*1024] | flags[512 ints]

typedef short short4v __attribute__((ext_vector_type(4)));
typedef short short8v __attribute__((ext_vector_type(8)));
typedef float float4v __attribute__((ext_vector_type(4)));

#define MAGIC 0x4D414749

static __device__ __forceinline__ short f2bf(float f) {
    unsigned u = __float_as_uint(f);
    u += 0x7fff + ((u >> 16) & 1);   // RNE; inputs never NaN here
    return (short)(u >> 16);
}
static __device__ __forceinline__ float rcpf(float x) { return __builtin_amdgcn_rcpf(x); }
static __device__ __forceinline__ short8v ld8(const unsigned short* p) {
    short4v lo = *(const short4v*)p;        // 8B-aligned LDS reads (pitch 132 shorts)
    short4v hi = *(const short4v*)(p + 4);
    return (short8v){lo[0],lo[1],lo[2],lo[3],hi[0],hi[1],hi[2],hi[3]};
}
static __device__ __forceinline__ float dot4(float4v a, float4v b) {
    return a[0]*b[0] + a[1]*b[1] + a[2]*b[2] + a[3]*b[3];
}

__global__ __launch_bounds__(256, 2) void hyp_fused(
    const float* __restrict__ x, const float* __restrict__ adj,
    const float* __restrict__ battp, const float* __restrict__ w,
    float* __restrict__ Yp, float* __restrict__ Sp, int* __restrict__ flags,
    float* __restrict__ out)
{
    __shared__ unsigned short sXI [16 * 132];   // X_I  bf16, row-major (i, dim)
    __shared__ unsigned short sXJ [128 * 132];  // X_J  bf16, row-major (j, dim)
    __shared__ unsigned short sXJt[128 * 132];  // X_J^T bf16, (dim, j)
    __shared__ unsigned short sW  [16 * 132];   // g weights bf16, (i, j)
    __shared__ float sX2J[128], sRJ[128];
    __shared__ float sX2I[16], sLI[16], sS[16];

    const int t    = threadIdx.x;
    const int lane = t & 63;
    const int wave = t >> 6;
    const int n    = lane & 15;   // mfma 16-col lane
    const int q    = lane >> 4;   // quad
    const int bx   = blockIdx.x;
    const int cch  = blockIdx.y;  // j-chunk
    const int i0   = bx * 16;
    const int j0   = cch * 128;
    const float batt = battp[0];

    // ---- adj prefetch (latency hidden behind staging) ----
    float adjv[2][4];
#pragma unroll
    for (int jsl = 0; jsl < 2; ++jsl) {
        int j = j0 + (wave * 2 + jsl) * 16 + n;
#pragma unroll
        for (int r = 0; r < 4; ++r)
            adjv[jsl][r] = adj[(i0 + q * 4 + r) * 1024 + j];
    }

    // ---- zero stat accumulators ----
    if (t < 128) { sX2J[t] = 0.f; sRJ[t] = 0.f; }
    if (t < 16)  { sX2I[t] = 0.f; sLI[t] = 0.f; sS[t] = 0.f; }
    __syncthreads();

    const float4v* x4 = (const float4v*)x;
    const float4v* w4 = (const float4v*)w;

    // ---- stage X_I (16x128) fp32->bf16 + i-stats (x2, x.w[:D]) ----
#pragma unroll
    for (int iter = 0; iter < 2; ++iter) {
        int idx = t + iter * 256;
        int r = idx >> 5, cc = idx & 31;         // 32-lane halves share r
        float4v v  = x4[(i0 + r) * 32 + cc];
        float4v w1 = w4[cc];
        short4v h = { f2bf(v[0]), f2bf(v[1]), f2bf(v[2]), f2bf(v[3]) };
        *(short4v*)&sXI[r * 132 + cc * 4] = h;
        float x2p = dot4(v, v), lp = dot4(v, w1);
#pragma unroll
        for (int m = 1; m < 32; m <<= 1) {
            x2p += __shfl_xor(x2p, m);
            lp  += __shfl_xor(lp, m);
        }
        if ((t & 31) == 0) { atomicAdd(&sX2I[r], x2p); atomicAdd(&sLI[r], lp); }
    }
    // ---- stage X_J row-major + transposed + j-stats (x2, x.w[D:]) ----
    // bid bits: [0..3]=dcL, [4..5]=jrL, [6..8]=jrH, [9]=dcH; 16-lane groups share jr
#pragma unroll
    for (int it = 0; it < 4; ++it) {
        int bid = t + it * 256;
        int jr = ((bid >> 4) & 3) | (((bid >> 6) & 7) << 2);   // 0..31
        int dc = (bid & 15) | (((bid >> 9) & 1) << 4);         // 0..31
        float4v w2 = w4[32 + dc];
        float4v v[4];
#pragma unroll
        for (int e = 0; e < 4; ++e)
            v[e] = x4[(j0 + jr * 4 + e) * 32 + dc];
        short4v h[4];
#pragma unroll
        for (int e = 0; e < 4; ++e) {
            h[e] = (short4v){ f2bf(v[e][0]), f2bf(v[e][1]), f2bf(v[e][2]), f2bf(v[e][3]) };
            *(short4v*)&sXJ[(jr * 4 + e) * 132 + dc * 4] = h[e];
        }
#pragma unroll
        for (int d = 0; d < 4; ++d) {
            short4v ht = (short4v){ h[0][d], h[1][d], h[2][d], h[3][d] };
            *(short4v*)&sXJt[(dc * 4 + d) * 132 + jr * 4] = ht;
        }
#pragma unroll
        for (int e = 0; e < 4; ++e) {
            float x2p = dot4(v[e], v[e]), rp = dot4(v[e], w2);
#pragma unroll
            for (int m = 1; m < 16; m <<= 1) {
                x2p += __shfl_xor(x2p, m);
                rp  += __shfl_xor(rp, m);
            }
            if ((t & 15) == 0) { atomicAdd(&sX2J[jr * 4 + e], x2p); atomicAdd(&sRJ[jr * 4 + e], rp); }
        }
    }
    __syncthreads();

    // ---- finalize stats: logmap0 scale f = atanh(pn)/pn ----
    if (t < 144) {
        float x2 = (t < 128) ? sX2J[t] : sX2I[t - 128];
        float pn = sqrtf(fmaxf(x2, 1e-15f));
        float uu = fminf(pn, 1.f - 1e-7f);
        float f  = 0.5f * __logf((1.f + uu) * rcpf(1.f - uu)) * rcpf(pn);
        if (t < 128) sRJ[t] *= f;
        else         sLI[t - 128] = sLI[t - 128] * f + batt;  // fold bias in
    }
    __syncthreads();

    // ---- per-lane stats + A-frags ----
    float x2i4[4], bi4[4], li4[4];
#pragma unroll
    for (int r = 0; r < 4; ++r) {
        x2i4[r] = sX2I[q * 4 + r];
        li4[r]  = sLI[q * 4 + r];
        bi4[r]  = 1.f - x2i4[r];
    }
    float x2j2[2], rj2[2];
#pragma unroll
    for (int jsl = 0; jsl < 2; ++jsl) {
        int js = wave * 2 + jsl;
        x2j2[jsl] = sX2J[js * 16 + n];
        rj2[jsl]  = sRJ[js * 16 + n];
    }
    short8v afrag[4];
#pragma unroll
    for (int kk = 0; kk < 4; ++kk)
        afrag[kk] = ld8(&sXI[n * 132 + kk * 32 + q * 8]);

    float Sacc[4] = {0.f, 0.f, 0.f, 0.f};

    // ---- phase A: G = X_I * X_J^T, per-pair scalar map -> sW ----
#pragma unroll
    for (int jsl = 0; jsl < 2; ++jsl) {
        int js = wave * 2 + jsl;
        int jrow = js * 16 + n;
        float4v acc = (float4v){0.f, 0.f, 0.f, 0.f};
#pragma unroll
        for (int kk = 0; kk < 4; ++kk) {
            short8v b = ld8(&sXJ[jrow * 132 + kk * 32 + q * 8]);
            acc = __builtin_amdgcn_mfma_f32_16x16x32_bf16(afrag[kk], b, acc, 0, 0, 0);
        }
        float x2j = x2j2[jsl];
        float rj  = rj2[jsl];
#pragma unroll
        for (int r = 0; r < 4; ++r) {
            float G     = acc[r];
            int   i     = q * 4 + r;
            float alpha = 1.f - 2.f * G + x2j;
            float den   = fmaxf(fmaf(x2i4[r], x2j, 1.f - 2.f * G), 1e-15f);
            float rdn   = rcpf(den);
            float bb    = bi4[r];
            float nn2   = alpha * alpha * x2i4[r] + bb * bb * x2j - 2.f * alpha * bb * G;
            float sub2  = nn2 * rdn * rdn;
            float sn    = sqrtf(fmaxf(sub2, 1e-15f));
            float uu    = fminf(sn, 1.f - 1e-7f);
            float at    = 0.5f * __logf((1.f + uu) * rcpf(1.f - uu));  // atanh(uu)
            float tt    = at * rcpf(sn);
            float z     = li4[r] + rj;                                  // batt folded in li
            float sig   = rcpf(1.f + __expf(-z));
            float g     = sig * adjv[jsl][r] * tt * rdn;
            Sacc[r]     = fmaf(g, alpha, Sacc[r]);
            sW[i * 132 + js * 16 + n] = (unsigned short)f2bf(g);
        }
    }
    __syncthreads();

    // ---- phase B: Y = W(16x128) * X_J(128x128) ----
    float4v accB[2];
    accB[0] = (float4v){0.f, 0.f, 0.f, 0.f};
    accB[1] = (float4v){0.f, 0.f, 0.f, 0.f};
#pragma unroll
    for (int nsl = 0; nsl < 2; ++nsl) {
        int ns = wave * 2 + nsl;
#pragma unroll
        for (int kk = 0; kk < 4; ++kk) {
            short8v a = ld8(&sW  [n * 132 + kk * 32 + q * 8]);
            short8v b = ld8(&sXJt[(ns * 16 + n) * 132 + kk * 32 + q * 8]);
            accB[nsl] = __builtin_amdgcn_mfma_f32_16x16x32_bf16(a, b, accB[nsl], 0, 0, 0);
        }
    }

    // ---- writer epilogue: partial stores + release flag ----
    float* Yc = Yp + cch * 131072;
#pragma unroll
    for (int nsl = 0; nsl < 2; ++nsl) {
        int ns = wave * 2 + nsl;
#pragma unroll
        for (int r = 0; r < 4; ++r)
            Yc[(i0 + q * 4 + r) * 128 + ns * 16 + n] = accB[nsl][r];
    }
#pragma unroll
    for (int r = 0; r < 4; ++r) {
        float v = Sacc[r];
        v += __shfl_xor(v, 1); v += __shfl_xor(v, 2);
        v += __shfl_xor(v, 4); v += __shfl_xor(v, 8);
        if (n == 0) atomicAdd(&sS[q * 4 + r], v);
    }
    __syncthreads();
    if (t < 16) Sp[cch * 1024 + i0 + t] = sS[t];
    __threadfence();           // order this thread's global stores (device scope)
    __syncthreads();           // all threads' fences done
    if (t == 0)
        __hip_atomic_store(&flags[bx * 8 + cch], MAGIC, __ATOMIC_RELEASE, __HIP_MEMORY_SCOPE_AGENT);

    // ---- owner epilogue: last-arrival sum + expmap + mobius add ----
    if ((bx & 7) != cch) return;
    if (t < 8) {
        while (__hip_atomic_load(&flags[bx * 8 + t], __ATOMIC_ACQUIRE, __HIP_MEMORY_SCOPE_AGENT) != MAGIC)
            __builtin_amdgcn_s_sleep(1);
    }
    __syncthreads();
    __threadfence();           // acquire: no stale partials

    int row  = t >> 4;         // 0..15
    int ds16 = t & 15;         // dim segment of 8
    const float4v* xr4 = x4 + (i0 + row) * 32 + ds16 * 2;
    float4v xa = xr4[0], xb = xr4[1];
    float xv[8] = { xa[0], xa[1], xa[2], xa[3], xb[0], xb[1], xb[2], xb[3] };
    float ya[8] = {0.f,0.f,0.f,0.f,0.f,0.f,0.f,0.f};
    float S = 0.f;
#pragma unroll
    for (int c2 = 0; c2 < 8; ++c2) {
        const float4v* yp4 = (const float4v*)(Yp + c2 * 131072 + (i0 + row) * 128) + ds16 * 2;
        float4v a = yp4[0], b = yp4[1];
        ya[0] += a[0]; ya[1] += a[1]; ya[2] += a[2]; ya[3] += a[3];
        ya[4] += b[0]; ya[5] += b[1]; ya[6] += b[2]; ya[7] += b[3];
        S += Sp[c2 * 1024 + i0 + row];
    }
    float x2p = dot4(xa, xa) + dot4(xb, xb);
#pragma unroll
    for (int m = 1; m < 16; m <<= 1) x2p += __shfl_xor(x2p, m);
    float bE = fmaxf(1.f - x2p, 1e-15f);
    float u[8], un2p = 0.f, xup = 0.f;
#pragma unroll
    for (int e = 0; e < 8; ++e) {
        u[e] = bE * (bE * ya[e] - S * xv[e]);
        un2p += u[e] * u[e];
        xup  += xv[e] * u[e];
    }
#pragma unroll
    for (int m = 1; m < 16; m <<= 1) {
        un2p += __shfl_xor(un2p, m);
        xup  += __shfl_xor(xup, m);
    }
    float un  = sqrtf(fmaxf(un2p, 1e-15f));
    float e2  = __expf(2.f * un * rcpf(bE));
    float th  = 1.f - 2.f * rcpf(e2 + 1.f);   // tanh(un/b)
    float s2  = th * rcpf(un);                 // tanh/norm
    float xy  = s2 * xup;
    float y2s = th * th;
    float coef = 1.f + 2.f * xy + y2s;
    float den  = fmaxf(1.f + 2.f * xy + x2p * y2s, 1e-15f);
    float rd   = rcpf(den);
    float4v o0 = { (coef*xv[0] + bE*s2*u[0])*rd, (coef*xv[1] + bE*s2*u[1])*rd,
                   (coef*xv[2] + bE*s2*u[2])*rd, (coef*xv[3] + bE*s2*u[3])*rd };
    float4v o1 = { (coef*xv[4] + bE*s2*u[4])*rd, (coef*xv[5] + bE*s2*u[5])*rd,
                   (coef*xv[6] + bE*s2*u[6])*rd, (coef*xv[7] + bE*s2*u[7])*rd };
    float4v* out4 = (float4v*)(out + (i0 + row) * 128) + ds16 * 2;
    out4[0] = o0; out4[1] = o1;
}

extern "C" void kernel_launch(void* const* d_in, const int* in_sizes, int n_in,
                              void* d_out, int out_size, void* d_ws, size_t ws_size,
                              hipStream_t stream) {
    const float* x    = (const float*)d_in[0];
    const float* adj  = (const float*)d_in[1];
    const float* w    = (const float*)d_in[2];
    const float* batt = (const float*)d_in[3];
    float* out = (float*)d_out;

    float* Yp    = (float*)d_ws;        // 8 * 131072 floats
    float* Sp    = Yp + 8 * 131072;     // 8 * 1024
    int*   flags = (int*)(Sp + 8 * 1024); // 512 ints (poisoned != MAGIC each launch)

    hipLaunchKernelGGL(hyp_fused, dim3(64, 8), dim3(256), 0, stream,
                       x, adj, batt, w, Yp, Sp, flags, out);
}

// Round 4
// 113.210 us; speedup vs baseline: 1.0558x; 1.0558x over previous
//
#include <hip/hip_runtime.h>
#include <math.h>

// HypAgg (Poincare ball, c=1), single dispatch, NO cross-block communication.
//   g_ij = att_ij * atanh(sn_ij)/sn_ij / den_ij
//   support_i = beta_i * ( -S_i x_i + beta_i Y_i ),  S=sum g*alpha, Y=sum g x_j
// Grid: 64 blocks; block bx owns i-rows [16bx,16bx+16) and loops all 8 j-chunks,
// carrying Y in MFMA accumulators and S in VGPRs across chunks. In-block epilogue.

typedef short short4v __attribute__((ext_vector_type(4)));
typedef short short8v __attribute__((ext_vector_type(8)));
typedef float float4v __attribute__((ext_vector_type(4)));

static __device__ __forceinline__ short f2bf(float f) {
    unsigned u = __float_as_uint(f);
    u += 0x7fff + ((u >> 16) & 1);   // RNE; inputs never NaN here
    return (short)(u >> 16);
}
static __device__ __forceinline__ float rcpf(float x) { return __builtin_amdgcn_rcpf(x); }
static __device__ __forceinline__ short8v ld8(const unsigned short* p) {
    short4v lo = *(const short4v*)p;        // 8B-aligned LDS reads (pitch 132 shorts)
    short4v hi = *(const short4v*)(p + 4);
    return (short8v){lo[0],lo[1],lo[2],lo[3],hi[0],hi[1],hi[2],hi[3]};
}
static __device__ __forceinline__ float dot4(float4v a, float4v b) {
    return a[0]*b[0] + a[1]*b[1] + a[2]*b[2] + a[3]*b[3];
}
static __device__ __forceinline__ float atanh_over(float pn) {   // atanh(min(pn,1-eps))/pn
    float uu = fminf(pn, 1.f - 1e-7f);
    return 0.5f * __logf((1.f + uu) * rcpf(1.f - uu)) * rcpf(pn);
}

__global__ __launch_bounds__(256) void hyp_fused(
    const float* __restrict__ x, const float* __restrict__ adj,
    const float* __restrict__ battp, const float* __restrict__ w,
    float* __restrict__ out)
{
    __shared__ unsigned short sXI [16 * 132];   // X_I  bf16, (i, dim)
    __shared__ unsigned short sXJ [128 * 132];  // X_J  bf16, (j, dim), current chunk
    __shared__ unsigned short sXJt[128 * 132];  // X_J^T bf16, (dim, j)
    __shared__ unsigned short sW  [16 * 132];   // g weights bf16, (i, j)
    __shared__ float sY[16 * 128];              // final Y tile (fp32)
    __shared__ float sX2J[128], sRJ[128];
    __shared__ float sX2I[16], sLI[16], sS[16];

    const int t    = threadIdx.x;
    const int lane = t & 63;
    const int wave = t >> 6;
    const int n    = lane & 15;   // mfma 16-col lane
    const int q    = lane >> 4;   // quad
    const int i0   = blockIdx.x * 16;
    const float batt = battp[0];

    const float4v* x4 = (const float4v*)x;
    const float4v* w4 = (const float4v*)w;

    // ---- zero stat accumulators ----
    if (t < 128) { sX2J[t] = 0.f; sRJ[t] = 0.f; }
    if (t < 16)  { sX2I[t] = 0.f; sLI[t] = 0.f; sS[t] = 0.f; }
    __syncthreads();

    // ---- stage X_I (16x128) fp32->bf16 + i-stats (x2, x.w[:D]) ----
#pragma unroll
    for (int iter = 0; iter < 2; ++iter) {
        int idx = t + iter * 256;
        int r = idx >> 5, cc = idx & 31;         // 32-lane halves share r
        float4v v  = x4[(i0 + r) * 32 + cc];
        float4v w1 = w4[cc];
        short4v h = { f2bf(v[0]), f2bf(v[1]), f2bf(v[2]), f2bf(v[3]) };
        *(short4v*)&sXI[r * 132 + cc * 4] = h;
        float x2p = dot4(v, v), lp = dot4(v, w1);
#pragma unroll
        for (int m = 1; m < 32; m <<= 1) {
            x2p += __shfl_xor(x2p, m);
            lp  += __shfl_xor(lp, m);
        }
        if ((t & 31) == 0) { atomicAdd(&sX2I[r], x2p); atomicAdd(&sLI[r], lp); }
    }
    __syncthreads();
    // ---- finalize i-stats: left_i = atanh(|x_i|)/|x_i| * (x_i.w1) + batt ----
    if (t < 16) {
        float pn = sqrtf(fmaxf(sX2I[t], 1e-15f));
        sLI[t] = sLI[t] * atanh_over(pn) + batt;
    }
    __syncthreads();

    // ---- per-lane i stats + A-frags (fixed for whole kernel) ----
    float x2i4[4], bi4[4], li4[4];
#pragma unroll
    for (int r = 0; r < 4; ++r) {
        x2i4[r] = sX2I[q * 4 + r];
        li4[r]  = sLI[q * 4 + r];
        bi4[r]  = 1.f - x2i4[r];
    }
    short8v afrag[4];
#pragma unroll
    for (int kk = 0; kk < 4; ++kk)
        afrag[kk] = ld8(&sXI[n * 132 + kk * 32 + q * 8]);

    float Sacc[4] = {0.f, 0.f, 0.f, 0.f};
    float4v accB[2];
    accB[0] = (float4v){0.f, 0.f, 0.f, 0.f};
    accB[1] = (float4v){0.f, 0.f, 0.f, 0.f};

    // ================= j-chunk loop (all state carried in registers) =============
    for (int cch = 0; cch < 8; ++cch) {
        const int j0 = cch * 128;

        // adj prefetch for this chunk (latency hidden behind staging+MFMA)
        float adjv[2][4];
#pragma unroll
        for (int jsl = 0; jsl < 2; ++jsl) {
            int j = j0 + (wave * 2 + jsl) * 16 + n;
#pragma unroll
            for (int r = 0; r < 4; ++r)
                adjv[jsl][r] = adj[(i0 + q * 4 + r) * 1024 + j];
        }

        // stage X_J row-major + transposed + j-stats (x2, x.w[D:])
        // bid bits: [0..3]=dcL, [4..5]=jrL, [6..8]=jrH, [9]=dcH; 16-lane groups share jr
#pragma unroll
        for (int it = 0; it < 4; ++it) {
            int bid = t + it * 256;
            int jr = ((bid >> 4) & 3) | (((bid >> 6) & 7) << 2);   // 0..31
            int dc = (bid & 15) | (((bid >> 9) & 1) << 4);         // 0..31
            float4v w2 = w4[32 + dc];
            float4v v[4];
#pragma unroll
            for (int e = 0; e < 4; ++e)
                v[e] = x4[(j0 + jr * 4 + e) * 32 + dc];
            short4v h[4];
#pragma unroll
            for (int e = 0; e < 4; ++e) {
                h[e] = (short4v){ f2bf(v[e][0]), f2bf(v[e][1]), f2bf(v[e][2]), f2bf(v[e][3]) };
                *(short4v*)&sXJ[(jr * 4 + e) * 132 + dc * 4] = h[e];
            }
#pragma unroll
            for (int d = 0; d < 4; ++d) {
                short4v ht = (short4v){ h[0][d], h[1][d], h[2][d], h[3][d] };
                *(short4v*)&sXJt[(dc * 4 + d) * 132 + jr * 4] = ht;
            }
#pragma unroll
            for (int e = 0; e < 4; ++e) {
                float x2p = dot4(v[e], v[e]), rp = dot4(v[e], w2);
#pragma unroll
                for (int m = 1; m < 16; m <<= 1) {
                    x2p += __shfl_xor(x2p, m);
                    rp  += __shfl_xor(rp, m);
                }
                if ((t & 15) == 0) { atomicAdd(&sX2J[jr * 4 + e], x2p); atomicAdd(&sRJ[jr * 4 + e], rp); }
            }
        }
        __syncthreads();

        // ---- phase A: G = X_I * X_J^T, per-pair scalar map -> sW, Sacc ----
#pragma unroll
        for (int jsl = 0; jsl < 2; ++jsl) {
            int js = wave * 2 + jsl;
            int jrow = js * 16 + n;
            float4v acc = (float4v){0.f, 0.f, 0.f, 0.f};
#pragma unroll
            for (int kk = 0; kk < 4; ++kk) {
                short8v b = ld8(&sXJ[jrow * 132 + kk * 32 + q * 8]);
                acc = __builtin_amdgcn_mfma_f32_16x16x32_bf16(afrag[kk], b, acc, 0, 0, 0);
            }
            float x2j = sX2J[jrow];
            float pnj = sqrtf(fmaxf(x2j, 1e-15f));
            float rj  = sRJ[jrow] * atanh_over(pnj);   // logmap0 scale inline (no barrier)
#pragma unroll
            for (int r = 0; r < 4; ++r) {
                float G     = acc[r];
                int   i     = q * 4 + r;
                float alpha = 1.f - 2.f * G + x2j;
                float den   = fmaxf(fmaf(x2i4[r], x2j, 1.f - 2.f * G), 1e-15f);
                float rdn   = rcpf(den);
                float bb    = bi4[r];
                float nn2   = alpha * alpha * x2i4[r] + bb * bb * x2j - 2.f * alpha * bb * G;
                float sn    = sqrtf(fmaxf(nn2 * rdn * rdn, 1e-15f));
                float tt    = atanh_over(sn);
                float z     = li4[r] + rj;                // batt folded in li
                float sig   = rcpf(1.f + __expf(-z));
                float g     = sig * adjv[jsl][r] * tt * rdn;
                Sacc[r]     = fmaf(g, alpha, Sacc[r]);
                sW[i * 132 + js * 16 + n] = (unsigned short)f2bf(g);
            }
        }
        __syncthreads();

        // ---- phase B: accB += W(16x128) * X_J(128x128); zero stats for next chunk ----
        if (t < 128) { sX2J[t] = 0.f; sRJ[t] = 0.f; }
#pragma unroll
        for (int nsl = 0; nsl < 2; ++nsl) {
            int ns = wave * 2 + nsl;
#pragma unroll
            for (int kk = 0; kk < 4; ++kk) {
                short8v a = ld8(&sW  [n * 132 + kk * 32 + q * 8]);
                short8v b = ld8(&sXJt[(ns * 16 + n) * 132 + kk * 32 + q * 8]);
                accB[nsl] = __builtin_amdgcn_mfma_f32_16x16x32_bf16(a, b, accB[nsl], 0, 0, 0);
            }
        }
        __syncthreads();   // sXJ/sXJt/sW free; stats zeroed for next chunk
    }

    // ================= in-block epilogue =================
    // S: reduce Sacc over the 16 n-lanes, accumulate per i-row
#pragma unroll
    for (int r = 0; r < 4; ++r) {
        float v = Sacc[r];
        v += __shfl_xor(v, 1); v += __shfl_xor(v, 2);
        v += __shfl_xor(v, 4); v += __shfl_xor(v, 8);
        if (n == 0) atomicAdd(&sS[q * 4 + r], v);
    }
    // Y: accumulators -> LDS
#pragma unroll
    for (int nsl = 0; nsl < 2; ++nsl) {
        int ns = wave * 2 + nsl;
#pragma unroll
        for (int r = 0; r < 4; ++r)
            sY[(q * 4 + r) * 128 + ns * 16 + n] = accB[nsl][r];
    }
    __syncthreads();

    // expmap + mobius add: thread t -> row t>>4, dim segment (t&15)*8
    int row = t >> 4;
    int seg = t & 15;
    const float4v* xr4 = x4 + (i0 + row) * 32 + seg * 2;
    float4v xa = xr4[0], xb = xr4[1];
    float xv[8] = { xa[0], xa[1], xa[2], xa[3], xb[0], xb[1], xb[2], xb[3] };
    const float* yrow = &sY[row * 128 + seg * 8];
    float S  = sS[row];
    float x2 = sX2I[row];
    float bE = fmaxf(1.f - x2, 1e-15f);
    float u[8], un2p = 0.f, xup = 0.f;
#pragma unroll
    for (int e = 0; e < 8; ++e) {
        u[e] = bE * (bE * yrow[e] - S * xv[e]);
        un2p += u[e] * u[e];
        xup  += xv[e] * u[e];
    }
#pragma unroll
    for (int m = 1; m < 16; m <<= 1) {
        un2p += __shfl_xor(un2p, m);
        xup  += __shfl_xor(xup, m);
    }
    float un  = sqrtf(fmaxf(un2p, 1e-15f));
    float e2  = __expf(2.f * un * rcpf(bE));
    float th  = 1.f - 2.f * rcpf(e2 + 1.f);   // tanh(un/b)
    float s2  = th * rcpf(un);                 // tanh/norm
    float xy  = s2 * xup;
    float y2s = th * th;
    float coef = 1.f + 2.f * xy + y2s;
    float den  = fmaxf(1.f + 2.f * xy + x2 * y2s, 1e-15f);
    float rd   = rcpf(den);
    float4v o0 = { (coef*xv[0] + bE*s2*u[0])*rd, (coef*xv[1] + bE*s2*u[1])*rd,
                   (coef*xv[2] + bE*s2*u[2])*rd, (coef*xv[3] + bE*s2*u[3])*rd };
    float4v o1 = { (coef*xv[4] + bE*s2*u[4])*rd, (coef*xv[5] + bE*s2*u[5])*rd,
                   (coef*xv[6] + bE*s2*u[6])*rd, (coef*xv[7] + bE*s2*u[7])*rd };
    float4v* out4 = (float4v*)(out + (i0 + row) * 128) + seg * 2;
    out4[0] = o0; out4[1] = o1;
}

extern "C" void kernel_launch(void* const* d_in, const int* in_sizes, int n_in,
                              void* d_out, int out_size, void* d_ws, size_t ws_size,
                              hipStream_t stream) {
    const float* x    = (const float*)d_in[0];
    const float* adj  = (const float*)d_in[1];
    const float* w    = (const float*)d_in[2];
    const float* batt = (const float*)d_in[3];
    float* out = (float*)d_out;
    (void)d_ws; (void)ws_size;

    hipLaunchKernelGGL(hyp_fused, dim3(64), dim3(256), 0, stream,
                       x, adj, batt, w, out);
}

// Round 5
// 72.984 us; speedup vs baseline: 1.6377x; 1.5512x over previous
//
#include <hip/hip_runtime.h>
#include <math.h>

// HypAgg (Poincare ball, c=1), 2 dispatches (graph dispatches are ~free).
//   g_ij = att_ij * atanh(sn_ij)/sn_ij / den_ij
//   support_i = beta_i * ( -S_i x_i + beta_i Y_i ),  S=sum g*alpha, Y=sum g x_j
// hyp_main: grid (64 i-tiles x 8 j-chunks), 2 blocks/CU, ZERO __shfl / atomics
// (each __shfl = ds_swizzle + dependent lgkmcnt(0) wait; ~128/chunk of them
//  was the hidden ~10K cyc/chunk cost in rounds 2-4).
// hyp_exp: sums the 8 per-chunk partials + expmap.
// ws floats: Yp[8*131072] | Sp[8*1024]

typedef short short4v __attribute__((ext_vector_type(4)));
typedef short short8v __attribute__((ext_vector_type(8)));
typedef float float4v __attribute__((ext_vector_type(4)));

static __device__ __forceinline__ short f2bf(float f) {
    unsigned u = __float_as_uint(f);
    u += 0x7fff + ((u >> 16) & 1);   // RNE; inputs never NaN here
    return (short)(u >> 16);
}
static __device__ __forceinline__ float bf2f(unsigned short s) {
    return __uint_as_float(((unsigned)s) << 16);
}
static __device__ __forceinline__ float rcpf(float x) { return __builtin_amdgcn_rcpf(x); }
static __device__ __forceinline__ short8v ld8(const unsigned short* p) {
    short4v lo = *(const short4v*)p;        // 8B-aligned LDS reads
    short4v hi = *(const short4v*)(p + 4);
    return (short8v){lo[0],lo[1],lo[2],lo[3],hi[0],hi[1],hi[2],hi[3]};
}
static __device__ __forceinline__ float dot4(float4v a, float4v b) {
    return a[0]*b[0] + a[1]*b[1] + a[2]*b[2] + a[3]*b[3];
}
static __device__ __forceinline__ float atanh_over(float pn) {   // atanh(min(pn,1-eps))/pn
    float uu = fminf(pn, 1.f - 1e-7f);
    return 0.5f * __logf((1.f + uu) * rcpf(1.f - uu)) * rcpf(pn);
}

// ---- LDS arena byte offsets ----
#define O_XI    0        // 16*132 shorts  = 4224
#define O_XJ    4224     // 128*132 shorts = 33792  [alias after B4: sSp 4*16*17 f]
#define O_XJT   38016    // 128*132 shorts = 33792
#define O_W     71808    // 16*132 shorts  = 4224   [alias before B3: sPx,sPr,sW2f,sPxI,sPlI]
#define O_PX    71808    // 256 f = 1024
#define O_PR    72832    // 256 f = 1024
#define O_W2F   73856    // 128 f = 512
#define O_PXI   74368    // 32 f = 128
#define O_PLI   74496    // 32 f = 128
#define O_X2J   76032    // 128 f = 512
#define O_RJ    76544    // 128 f = 512
#define O_X2I   77056    // 16 f = 64
#define O_LI    77120    // 16 f = 64
#define LDS_SZ  77184    // 75.4 KB -> 2 blocks/CU

__global__ __launch_bounds__(256, 2) void hyp_main(
    const float* __restrict__ x, const float* __restrict__ adj,
    const float* __restrict__ battp, const float* __restrict__ w,
    float* __restrict__ Yp, float* __restrict__ Sp)
{
    __shared__ __align__(16) char arena[LDS_SZ];
    unsigned short* sXI  = (unsigned short*)(arena + O_XI);
    unsigned short* sXJ  = (unsigned short*)(arena + O_XJ);
    unsigned short* sXJt = (unsigned short*)(arena + O_XJT);
    unsigned short* sW   = (unsigned short*)(arena + O_W);
    float* sPx  = (float*)(arena + O_PX);
    float* sPr  = (float*)(arena + O_PR);
    float* sW2f = (float*)(arena + O_W2F);
    float* sPxI = (float*)(arena + O_PXI);
    float* sPlI = (float*)(arena + O_PLI);
    float* sX2J = (float*)(arena + O_X2J);
    float* sRJ  = (float*)(arena + O_RJ);
    float* sX2I = (float*)(arena + O_X2I);
    float* sLI  = (float*)(arena + O_LI);
    float* sSp  = (float*)(arena + O_XJ);   // alias over sXJ (dead after phase A)

    const int t    = threadIdx.x;
    const int lane = t & 63;
    const int wave = t >> 6;
    const int n    = lane & 15;   // mfma 16-col lane
    const int q    = lane >> 4;   // quad
    const int i0   = blockIdx.x * 16;
    const int cch  = blockIdx.y;
    const int j0   = cch * 128;
    const float batt = battp[0];

    const float4v* x4 = (const float4v*)x;
    const float4v* w4 = (const float4v*)w;

    // ---- adj prefetch (8 coalesced loads, hidden behind staging) ----
    float adjv[2][4];
#pragma unroll
    for (int jsl = 0; jsl < 2; ++jsl) {
        int j = j0 + (wave * 2 + jsl) * 16 + n;
#pragma unroll
        for (int r = 0; r < 4; ++r)
            adjv[jsl][r] = adj[(i0 + q * 4 + r) * 1024 + j];
    }

    // ---- phase 0: stage everything (plain LDS writes only) ----
    if (t < 32) *(float4v*)&sW2f[t * 4] = w4[32 + t];
    if (t < 32) {    // i-stat partials from GLOBAL fp32: i=t>>1, half=t&1
        int i = t >> 1, half = t & 1;
        float x2p = 0.f, lp = 0.f;
#pragma unroll
        for (int k = 0; k < 16; ++k) {
            float4v v  = x4[(i0 + i) * 32 + half * 16 + k];
            float4v wv = w4[half * 16 + k];
            x2p += dot4(v, v);
            lp  += dot4(v, wv);
        }
        sPxI[t] = x2p; sPlI[t] = lp;
    }
    // stage X_I (16x128) fp32->bf16
#pragma unroll
    for (int iter = 0; iter < 2; ++iter) {
        int idx = t + iter * 256;
        int r = idx >> 5, cc = idx & 31;
        float4v v = x4[(i0 + r) * 32 + cc];
        short4v h = { f2bf(v[0]), f2bf(v[1]), f2bf(v[2]), f2bf(v[3]) };
        *(short4v*)&sXI[r * 132 + cc * 4] = h;
    }
    // stage X_J row-major + transposed via 4x4 micro-blocks
    // bid bits: [0..3]=dcL, [4..5]=jrL, [6..8]=jrH, [9]=dcH
#pragma unroll
    for (int it = 0; it < 4; ++it) {
        int bid = t + it * 256;
        int jr = ((bid >> 4) & 3) | (((bid >> 6) & 7) << 2);   // 0..31
        int dc = (bid & 15) | (((bid >> 9) & 1) << 4);         // 0..31
        float4v v[4];
#pragma unroll
        for (int e = 0; e < 4; ++e)
            v[e] = x4[(j0 + jr * 4 + e) * 32 + dc];
        short4v h[4];
#pragma unroll
        for (int e = 0; e < 4; ++e) {
            h[e] = (short4v){ f2bf(v[e][0]), f2bf(v[e][1]), f2bf(v[e][2]), f2bf(v[e][3]) };
            *(short4v*)&sXJ[(jr * 4 + e) * 132 + dc * 4] = h[e];
        }
#pragma unroll
        for (int d = 0; d < 4; ++d) {
            short4v ht = (short4v){ h[0][d], h[1][d], h[2][d], h[3][d] };
            *(short4v*)&sXJt[(dc * 4 + d) * 132 + jr * 4] = ht;
        }
    }
    __syncthreads();   // B1

    // ---- phase 0.5: j-stats, one half-row per thread, independent reads ----
    {
        int j = t >> 1, half = t & 1;
        const unsigned short* rowp = &sXJ[j * 132 + half * 64];
        float x2p = 0.f, rp = 0.f;
#pragma unroll
        for (int k = 0; k < 8; ++k) {
            short8v v = ld8(rowp + k * 8);
#pragma unroll
            for (int e = 0; e < 8; ++e) {
                float f = bf2f((unsigned short)v[e]);
                x2p = fmaf(f, f, x2p);
                rp  = fmaf(f, sW2f[half * 64 + k * 8 + e], rp);
            }
        }
        sPx[t] = x2p; sPr[t] = rp;
    }
    __syncthreads();   // B2

    // ---- phase 0.75: finalize stats ----
    if (t < 128) {
        float x2 = sPx[2 * t] + sPx[2 * t + 1];
        float r  = sPr[2 * t] + sPr[2 * t + 1];
        float pn = sqrtf(fmaxf(x2, 1e-15f));
        sX2J[t] = x2;
        sRJ[t]  = r * atanh_over(pn);
    } else if (t < 144) {
        int i = t - 128;
        float x2 = sPxI[2 * i] + sPxI[2 * i + 1];
        float l  = sPlI[2 * i] + sPlI[2 * i + 1];
        float pn = sqrtf(fmaxf(x2, 1e-15f));
        sX2I[i] = x2;
        sLI[i]  = l * atanh_over(pn) + batt;
    }
    __syncthreads();   // B3

    float x2i4[4], bi4[4], li4[4];
#pragma unroll
    for (int r = 0; r < 4; ++r) {
        x2i4[r] = sX2I[q * 4 + r];
        li4[r]  = sLI[q * 4 + r];
        bi4[r]  = 1.f - x2i4[r];
    }
    short8v afrag[4];
#pragma unroll
    for (int kk = 0; kk < 4; ++kk)
        afrag[kk] = ld8(&sXI[n * 132 + kk * 32 + q * 8]);

    float Sacc[4] = {0.f, 0.f, 0.f, 0.f};

    // ---- phase A: G = X_I * X_J^T, per-pair scalar map -> sW, Sacc ----
#pragma unroll
    for (int jsl = 0; jsl < 2; ++jsl) {
        int js = wave * 2 + jsl;
        int jrow = js * 16 + n;
        float4v acc = (float4v){0.f, 0.f, 0.f, 0.f};
#pragma unroll
        for (int kk = 0; kk < 4; ++kk) {
            short8v b = ld8(&sXJ[jrow * 132 + kk * 32 + q * 8]);
            acc = __builtin_amdgcn_mfma_f32_16x16x32_bf16(afrag[kk], b, acc, 0, 0, 0);
        }
        float x2j = sX2J[jrow];
        float rj  = sRJ[jrow];
#pragma unroll
        for (int r = 0; r < 4; ++r) {
            float G     = acc[r];
            int   i     = q * 4 + r;
            float alpha = 1.f - 2.f * G + x2j;
            float den   = fmaxf(fmaf(x2i4[r], x2j, 1.f - 2.f * G), 1e-15f);
            float rdn   = rcpf(den);
            float bb    = bi4[r];
            float nn2   = alpha * alpha * x2i4[r] + bb * bb * x2j - 2.f * alpha * bb * G;
            float sn    = sqrtf(fmaxf(nn2 * rdn * rdn, 1e-15f));
            float tt    = atanh_over(sn);
            float z     = li4[r] + rj;
            float sig   = rcpf(1.f + __expf(-z));
            float g     = sig * adjv[jsl][r] * tt * rdn;
            Sacc[r]     = fmaf(g, alpha, Sacc[r]);
            sW[i * 132 + js * 16 + n] = (unsigned short)f2bf(g);
        }
    }
    __syncthreads();   // B4: sW complete; sXJ dead from here (sSp alias ok)

    // ---- phase B: Y = W(16x128) * X_J(128x128) via sXJt ----
    float4v accB[2];
    accB[0] = (float4v){0.f, 0.f, 0.f, 0.f};
    accB[1] = (float4v){0.f, 0.f, 0.f, 0.f};
#pragma unroll
    for (int nsl = 0; nsl < 2; ++nsl) {
        int ns = wave * 2 + nsl;
#pragma unroll
        for (int kk = 0; kk < 4; ++kk) {
            short8v a = ld8(&sW  [n * 132 + kk * 32 + q * 8]);
            short8v b = ld8(&sXJt[(ns * 16 + n) * 132 + kk * 32 + q * 8]);
            accB[nsl] = __builtin_amdgcn_mfma_f32_16x16x32_bf16(a, b, accB[nsl], 0, 0, 0);
        }
    }

    // ---- epilogue: Y partial stores + S via per-wave LDS slots (no shfl/atomics) ----
    float* Yc = Yp + cch * 131072;
#pragma unroll
    for (int nsl = 0; nsl < 2; ++nsl) {
        int ns = wave * 2 + nsl;
#pragma unroll
        for (int r = 0; r < 4; ++r)
            Yc[(i0 + q * 4 + r) * 128 + ns * 16 + n] = accB[nsl][r];
    }
#pragma unroll
    for (int r = 0; r < 4; ++r)
        sSp[wave * 272 + (q * 4 + r) * 17 + n] = Sacc[r];
    __syncthreads();   // B5
    if (t < 16) {
        float s = 0.f;
#pragma unroll
        for (int wv = 0; wv < 4; ++wv)
#pragma unroll
            for (int k = 0; k < 16; ++k) s += sSp[wv * 272 + t * 17 + k];
        Sp[cch * 1024 + i0 + t] = s;
    }
}

// ---------------- kernel 2: sum partials + expmap ----------------
__global__ __launch_bounds__(256) void hyp_exp(
    const float* __restrict__ x, const float* __restrict__ Yp,
    const float* __restrict__ Sp, float* __restrict__ out)
{
    const float4v* x4 = (const float4v*)x;
    int i0  = blockIdx.x * 16;
    int t   = threadIdx.x;
    int row = t >> 4;
    int seg = t & 15;
    const float4v* xr4 = x4 + (i0 + row) * 32 + seg * 2;
    float4v xa = xr4[0], xb = xr4[1];
    float xv[8] = { xa[0], xa[1], xa[2], xa[3], xb[0], xb[1], xb[2], xb[3] };
    float ya[8] = {0.f,0.f,0.f,0.f,0.f,0.f,0.f,0.f};
    float S = 0.f;
#pragma unroll
    for (int c2 = 0; c2 < 8; ++c2) {
        const float4v* yp4 = (const float4v*)(Yp + c2 * 131072 + (i0 + row) * 128) + seg * 2;
        float4v a = yp4[0], b = yp4[1];
        ya[0] += a[0]; ya[1] += a[1]; ya[2] += a[2]; ya[3] += a[3];
        ya[4] += b[0]; ya[5] += b[1]; ya[6] += b[2]; ya[7] += b[3];
        S += Sp[c2 * 1024 + i0 + row];
    }
    float x2p = dot4(xa, xa) + dot4(xb, xb);
#pragma unroll
    for (int m = 1; m < 16; m <<= 1) x2p += __shfl_xor(x2p, m);
    float bE = fmaxf(1.f - x2p, 1e-15f);
    float u[8], un2p = 0.f, xup = 0.f;
#pragma unroll
    for (int e = 0; e < 8; ++e) {
        u[e] = bE * (bE * ya[e] - S * xv[e]);
        un2p += u[e] * u[e];
        xup  += xv[e] * u[e];
    }
#pragma unroll
    for (int m = 1; m < 16; m <<= 1) {
        un2p += __shfl_xor(un2p, m);
        xup  += __shfl_xor(xup, m);
    }
    float un  = sqrtf(fmaxf(un2p, 1e-15f));
    float e2  = __expf(2.f * un * rcpf(bE));
    float th  = 1.f - 2.f * rcpf(e2 + 1.f);   // tanh(un/b)
    float s2  = th * rcpf(un);
    float xy  = s2 * xup;
    float y2s = th * th;
    float coef = 1.f + 2.f * xy + y2s;
    float den  = fmaxf(1.f + 2.f * xy + x2p * y2s, 1e-15f);
    float rd   = rcpf(den);
    float4v o0 = { (coef*xv[0] + bE*s2*u[0])*rd, (coef*xv[1] + bE*s2*u[1])*rd,
                   (coef*xv[2] + bE*s2*u[2])*rd, (coef*xv[3] + bE*s2*u[3])*rd };
    float4v o1 = { (coef*xv[4] + bE*s2*u[4])*rd, (coef*xv[5] + bE*s2*u[5])*rd,
                   (coef*xv[6] + bE*s2*u[6])*rd, (coef*xv[7] + bE*s2*u[7])*rd };
    float4v* out4 = (float4v*)(out + (i0 + row) * 128) + seg * 2;
    out4[0] = o0; out4[1] = o1;
}

extern "C" void kernel_launch(void* const* d_in, const int* in_sizes, int n_in,
                              void* d_out, int out_size, void* d_ws, size_t ws_size,
                              hipStream_t stream) {
    const float* x    = (const float*)d_in[0];
    const float* adj  = (const float*)d_in[1];
    const float* w    = (const float*)d_in[2];
    const float* batt = (const float*)d_in[3];
    float* out = (float*)d_out;

    float* Yp = (float*)d_ws;           // 8 * 131072 floats
    float* Sp = Yp + 8 * 131072;        // 8 * 1024 floats

    hipLaunchKernelGGL(hyp_main, dim3(64, 8), dim3(256), 0, stream,
                       x, adj, batt, w, Yp, Sp);
    hipLaunchKernelGGL(hyp_exp, dim3(64), dim3(256), 0, stream, x, Yp, Sp, out);
}